// Round 7
// baseline (3017.628 us; speedup 1.0000x reference)
//
#include <hip/hip_runtime.h>
#include <hip/hip_fp16.h>
#include <math.h>

typedef _Float16 f16;
typedef __attribute__((ext_vector_type(8))) _Float16 f16x8;
typedef __attribute__((ext_vector_type(4))) float f32x4;
typedef unsigned int u32;

#define B_ 128
#define S_ 256
#define I_ 128
#define H_ 1024
#define G_ 4096
#define T_ 128
#define F_ 64

// ---------------- workspace layout (bytes) ----------------
#define BAR_OFF   0ull
#define HB0_OFF   4096ull
#define HB1_OFF   (HB0_OFF + 262144ull)
#define X16_OFF   (HB1_OFF + 262144ull)          // [S][B][I] f16
#define BPE_OFF   (X16_OFF + 8388608ull)         // enc B-frag pack: [64][36][4][64][8] f16
#define BPD_OFF   (BPE_OFF + 9437184ull)         // dec W_eff pack:  [64][32][4][64][8] f16
#define DWT_OFF   (BPD_OFF + 8388608ull)         // (dense_W - out_W)^T : [1024][64] f32
#define BEN_OFF   (DWT_OFF + 262144ull)          // enc bias [4096] f32
#define BDE_OFF   (BEN_OFF + 16384ull)           // dec bias (t>=2) [4096] f32
#define BBA_OFF   (BDE_OFF + 16384ull)           // dec base bias (b_ih+b_hh) [4096] f32
#define OWP_OFF   (BBA_OFF + 16384ull)           // out_W pack [32][4][64][8] f16
#define HIST_OFF  (OWP_OFF + 131072ull)          // dec h history [128][128][1024] f16
// total ~60.7 MB

// =================== prep kernel 1 ===================
__global__ void k_prep(const float* __restrict__ x,
                       const float* __restrict__ eWih, const float* __restrict__ eWhh,
                       const float* __restrict__ eb_ih, const float* __restrict__ eb_hh,
                       const float* __restrict__ dW,   const float* __restrict__ db,
                       const float* __restrict__ dWih, const float* __restrict__ db_ih,
                       const float* __restrict__ db_hh,
                       const float* __restrict__ oW,   const float* __restrict__ ob,
                       char* ws)
{
  u32*  bar = (u32*)(ws + BAR_OFF);
  f16*  h0  = (f16*)(ws + HB0_OFF);
  f16*  x16 = (f16*)(ws + X16_OFF);
  f16*  bpe = (f16*)(ws + BPE_OFF);
  float* dwt = (float*)(ws + DWT_OFF);
  float* ben = (float*)(ws + BEN_OFF);
  float* bde = (float*)(ws + BDE_OFF);
  float* bba = (float*)(ws + BBA_OFF);
  f16*  owp = (f16*)(ws + OWP_OFF);

  int tid = blockIdx.x*blockDim.x + threadIdx.x;
  int np  = gridDim.x*blockDim.x;

  // re-zero barrier state every call (graph replay determinism)
  for (int i = tid; i < 1024; i += np) bar[i] = 0u;
  for (int i = tid; i < B_*H_; i += np) h0[i] = (f16)0.f;

  for (int i = tid; i < S_*B_*I_; i += np) {
    int ii = i & 127; int b = (i >> 7) & 127; int s = i >> 14;
    x16[i] = (f16)x[((size_t)b*S_ + s)*I_ + ii];
  }

  for (int g = tid; g < G_; g += np) {
    ben[g] = eb_ih[g] + eb_hh[g];
    float base = db_ih[g] + db_hh[g];
    bba[g] = base;
    float acc = base;
    for (int f = 0; f < F_; ++f) acc += ob[f] * dWih[(size_t)g*F_ + f];
    bde[g] = acc;
  }

  for (int i = tid; i < H_*F_; i += np) {
    int f = i & 63; int k = i >> 6;
    dwt[i] = dW[(size_t)f*H_ + k] - oW[(size_t)f*H_ + k];
  }

  // encoder B-frag pack: k-order = [x(128) | h(1024)]
  for (int i = tid; i < 64*36*4*64*8; i += np) {
    int j = i & 7; int lane = (i >> 3) & 63; int nt = (i >> 9) & 3;
    int rest = i >> 11; int q = rest % 36; int wgN = rest / 36;
    int colg = nt*H_ + wgN*16 + (lane & 15);
    int k = q*32 + ((lane >> 4) << 3) + j;
    float v = (k < 128) ? eWih[(size_t)colg*I_ + k] : eWhh[(size_t)colg*H_ + (k - 128)];
    bpe[i] = (f16)v;
  }

  // out_W pack for final GEMM
  for (int i = tid; i < 32*4*64*8; i += np) {
    int j = i & 7; int lane = (i >> 3) & 63; int nt = (i >> 9) & 3; int q = i >> 11;
    int f = nt*16 + (lane & 15);
    int k = q*32 + ((lane >> 4) << 3) + j;
    owp[i] = (f16)oW[(size_t)f*H_ + k];
  }
}

// =================== prep kernel 2: W_eff = dec_W_hh + dec_W_ih @ out_W ===================
__global__ void k_packdec(const float* __restrict__ dWih, const float* __restrict__ dWhh,
                          const float* __restrict__ oW, char* ws)
{
  f16* bpd = (f16*)(ws + BPD_OFF);
  __shared__ float sW[4][64];
  int cg0 = blockIdx.x * 4;
  for (int i = threadIdx.x; i < 256; i += 256)
    sW[i >> 6][i & 63] = dWih[(size_t)(cg0 + (i >> 6))*64 + (i & 63)];
  __syncthreads();
  for (int u = 0; u < 4; ++u) {
    int colg = cg0 + u;
    for (int k = threadIdx.x; k < 1024; k += 256) {
      float acc = dWhh[(size_t)colg*1024 + k];
      #pragma unroll
      for (int f = 0; f < 64; ++f) acc += sW[u][f] * oW[(size_t)f*1024 + k];
      int nt = colg >> 10, w16 = colg & 1023;
      int wgN = w16 >> 4, cl = w16 & 15;
      int q = k >> 5, hi = (k >> 3) & 3, j = k & 7;
      bpd[((((size_t)wgN*32 + q)*4 + nt)*64 + hi*16 + cl)*8 + j] = (f16)acc;
    }
  }
}

// =================== persistent LSTM kernel ===================
// grid 256 = 1 WG/CU. NO fences (agent fences = buffer_wbl2/inv = 27us/step, r5).
// h-exchange is write-through/read-through at IF via sc0 sc1 asm ops; barrier is
// relaxed atomics per wgM (only the 64 WGs sharing a batch tile must sync).
// bw[] weight fragments pinned in VGPRs via asm "+v" (r5: compiler remat'd them).

#define LDg(DST, PTR) \
  asm volatile("global_load_dwordx4 %0, %1, off sc0 sc1" : "=v"(DST) : "v"(PTR))

#define WAITV(N) do { \
    asm volatile("s_waitcnt vmcnt(" #N ")" ::: "memory"); \
    __builtin_amdgcn_sched_barrier(0); \
  } while (0)

#define ISSUE4(SLOT, BASEPTR, Q0) do { \
    LDg(af[SLOT][0], (BASEPTR) + (Q0)*32); \
    LDg(af[SLOT][1], (BASEPTR) + ((Q0)+1)*32); \
    LDg(af[SLOT][2], (BASEPTR) + ((Q0)+2)*32); \
    LDg(af[SLOT][3], (BASEPTR) + ((Q0)+3)*32); \
  } while (0)

#define MFMA8(SLOT, QB) do { \
    _Pragma("unroll") \
    for (int i_ = 0; i_ < 4; ++i_) { \
      acc0 = __builtin_amdgcn_mfma_f32_16x16x32_f16(af[SLOT][i_], bw[(QB)+i_][0], acc0, 0,0,0); \
      acc1 = __builtin_amdgcn_mfma_f32_16x16x32_f16(af[SLOT][i_], bw[(QB)+i_][1], acc1, 0,0,0); \
    } \
  } while (0)

#define EPILOGUE() do { \
    _Pragma("unroll") \
    for (int reg = 0; reg < 4; ++reg) { \
      int cr = mrow + ((l >> 4) << 2) + reg; \
      gsm[cr][nh*32 + (l & 15)]      = acc0[reg]; \
      gsm[cr][nh*32 + 16 + (l & 15)] = acc1[reg]; \
    } \
    __syncthreads(); \
  } while (0)

// thread tid owns cells (r, j2) and (r, j2+1): r=tid>>3, j2=(tid&7)*2.
// h written as one 4B sc0sc1 store; c lives in creg0/creg1 across all 384 steps.
#define POINTWISE(BSL, USEB1, DOHIST, TT) do { \
    const float* br_ = (USEB1) ? &b1sm[pr][0] : (BSL); \
    float h2_[2]; \
    _Pragma("unroll") \
    for (int u_ = 0; u_ < 2; ++u_) { \
      int c_ = pj2 + u_; \
      float gi = gsm[pr][c_]      + br_[c_]; \
      float gf = gsm[pr][16 + c_] + br_[16 + c_]; \
      float gg = gsm[pr][32 + c_] + br_[32 + c_]; \
      float go = gsm[pr][48 + c_] + br_[48 + c_]; \
      float si = 1.f/(1.f + __expf(-gi)); \
      float sf = 1.f/(1.f + __expf(-gf)); \
      float sg = tanhf(gg); \
      float so = 1.f/(1.f + __expf(-go)); \
      float cn = sf*(u_ ? creg1 : creg0) + si*sg; \
      if (u_) creg1 = cn; else creg0 = cn; \
      h2_[u_] = so * tanhf(cn); \
    } \
    u32 hv_ = ((u32)__builtin_bit_cast(unsigned short, (f16)h2_[0])) \
            | (((u32)__builtin_bit_cast(unsigned short, (f16)h2_[1])) << 16); \
    f16* hp_ = hdst + (size_t)pbg*H_ + phc; \
    asm volatile("global_store_dword %0, %1, off sc0 sc1" :: "v"(hp_), "v"(hv_) : "memory"); \
    if (DOHIST) *(u32*)(hist + ((size_t)((TT) - 1)*B_ + pbg)*H_ + phc) = hv_; \
  } while (0)

// relaxed-atomic barrier over the 64 WGs sharing wgM. No fences: h stores are
// write-through (drained by vmcnt(0)), h loads bypass L1/L2, counters are
// IF-coherent atomics. flag at bar[wgM*32], counter at bar[128+wgM*32].
#define GRIDBAR(ID) do { \
    asm volatile("s_waitcnt vmcnt(0)" ::: "memory"); \
    __syncthreads(); \
    if (tid == 0) { \
      u32 a = __hip_atomic_fetch_add(cnt, 1u, __ATOMIC_RELAXED, __HIP_MEMORY_SCOPE_AGENT); \
      if (a == (u32)((ID)*64 + 63)) { \
        __hip_atomic_store(flg, (u32)((ID) + 1), __ATOMIC_RELAXED, __HIP_MEMORY_SCOPE_AGENT); \
      } \
      while (__hip_atomic_load(flg, __ATOMIC_RELAXED, __HIP_MEMORY_SCOPE_AGENT) < (u32)((ID) + 1)) { \
        __builtin_amdgcn_s_sleep(1); \
      } \
    } \
    __syncthreads(); \
  } while (0)

#define CONSUMEY(P, KB) do { \
    _Pragma("unroll") \
    for (int i_ = 0; i_ < 8; ++i_) { \
      _Pragma("unroll") \
      for (int j_ = 0; j_ < 8; ++j_) { \
        float hv = (float)(P)[i_][j_]; \
        int k_ = (KB)*64 + i_*8 + j_; \
        _Pragma("unroll") \
        for (int ff = 0; ff < 8; ++ff) za[ff] += hv * dwt[k_*F_ + f0 + ff]; \
      } \
    } \
  } while (0)

__global__ __launch_bounds__(256, 1) void k_lstm(
    const f16* __restrict__ x16, const f16* __restrict__ bpe, const f16* __restrict__ bpd,
    const float* __restrict__ dwt, const float* __restrict__ ben, const float* __restrict__ bde,
    const float* __restrict__ bba, const float* __restrict__ db,  const float* __restrict__ dWih,
    f16* hb0, f16* hb1, f16* hist, u32* bar)
{
  __shared__ float gsm[32][68];   // padded: breaks 4/8-way bank aliasing
  __shared__ float b1sm[32][64];
  __shared__ float zsm[32][F_];
  __shared__ float bslE[64], bslD[64];

  const int tid = threadIdx.x;
  const int w = tid >> 6, l = tid & 63;
  const int wg  = blockIdx.x;
  const int wgM = wg >> 6;     // 0..3 : batch tile
  const int wgN = wg & 63;     // 0..63: hidden tile
  const int nh   = w & 1;
  const int mrow = (w >> 1) * 16;
  const int arow = wgM*32 + mrow + (l & 15);   // global batch row this lane reads (A)
  const int koff = (l >> 4) << 3;              // k sub-offset within each 32-chunk
  const int pr  = tid >> 3;                    // pointwise row
  const int pj2 = (tid & 7) * 2;               // pointwise col pair
  const int pbg = wgM*32 + pr;
  const int phc = wgN*16 + pj2;
  u32* flg = bar + wgM*32;
  u32* cnt = bar + 128 + wgM*32;

  for (int cc = tid; cc < 64; cc += 256) {
    int colg = (cc >> 4)*H_ + wgN*16 + (cc & 15);
    bslE[cc] = ben[colg];
    bslD[cc] = bde[colg];
  }

  // encoder B fragments -> pinned VGPRs (36 ksteps x 2 col-tiles = 288 VGPR)
  f16x8 bw[36][2];
  #pragma unroll
  for (int q = 0; q < 36; ++q) {
    #pragma unroll
    for (int n = 0; n < 2; ++n) {
      int nt = nh*2 + n;
      bw[q][n] = *(const f16x8*)(bpe + ((((size_t)wgN*36 + q)*4 + nt)*64 + l)*8);
      asm volatile("" : "+v"(bw[q][n]));   // pin: defeat rematerialization (r5: VGPR=172 proved remat)
    }
  }
  float creg0 = 0.f, creg1 = 0.f;
  f16x8 af[3][4];
  __syncthreads();

  // ---------------- encoder: 256 steps, K = 128(x) + 1024(h) ----------------
  for (int t = 0; t < S_; ++t) {
    const f16* hsrc = (t & 1) ? hb1 : hb0;
    f16*       hdst = (t & 1) ? hb0 : hb1;
    const f16* xr = x16 + ((size_t)t*B_ + arow)*I_ + koff;
    const f16* hr = hsrc + (size_t)arow*H_ + koff;
    f32x4 acc0 = {0.f,0.f,0.f,0.f}, acc1 = {0.f,0.f,0.f,0.f};
    ISSUE4(0, xr, 0);
    ISSUE4(1, hr, 0);
    ISSUE4(2, hr, 4);
    WAITV(8); MFMA8(0, 0);  ISSUE4(0, hr, 8);
    WAITV(8); MFMA8(1, 4);  ISSUE4(1, hr, 12);
    WAITV(8); MFMA8(2, 8);  ISSUE4(2, hr, 16);
    WAITV(8); MFMA8(0, 12); ISSUE4(0, hr, 20);
    WAITV(8); MFMA8(1, 16); ISSUE4(1, hr, 24);
    WAITV(8); MFMA8(2, 20); ISSUE4(2, hr, 28);
    WAITV(8); MFMA8(0, 24);
    WAITV(4); MFMA8(1, 28);
    WAITV(0); MFMA8(2, 32);
    EPILOGUE();
    POINTWISE(bslE, false, false, t);
    GRIDBAR(t);
  }

  // ---------------- phase Y: z = h_n (dense_W - out_W)^T + dense_b ; bias1 ----------------
  {
    int f0 = (tid & 7) * 8;
    float za[8];
    #pragma unroll
    for (int ff = 0; ff < 8; ++ff) za[ff] = db[f0 + ff];
    const f16* hn = hb0 + (size_t)pbg*H_;   // h_n rows of this WG's batch tile (sc-read: L2 stale)
    f16x8 pa[8], pb[8];
    #pragma unroll
    for (int i = 0; i < 8; ++i) LDg(pa[i], hn + i*8);
    #pragma unroll
    for (int i = 0; i < 8; ++i) LDg(pb[i], hn + 64 + i*8);
    #pragma unroll
    for (int kb = 0; kb < 7; ++kb) {
      WAITV(8);
      CONSUMEY(pa, kb*2);
      #pragma unroll
      for (int i = 0; i < 8; ++i) LDg(pa[i], hn + (kb*2+2)*64 + i*8);
      WAITV(8);
      CONSUMEY(pb, kb*2+1);
      #pragma unroll
      for (int i = 0; i < 8; ++i) LDg(pb[i], hn + (kb*2+3)*64 + i*8);
    }
    WAITV(8); CONSUMEY(pa, 14);
    WAITV(0); CONSUMEY(pb, 15);
    #pragma unroll
    for (int ff = 0; ff < 8; ++ff) zsm[pr][f0 + ff] = za[ff];
    __syncthreads();
    int cc0 = (tid & 7) * 8;
    for (int u = 0; u < 8; ++u) {
      int cc = cc0 + u;
      int colg = (cc >> 4)*H_ + wgN*16 + (cc & 15);
      float a = bba[colg];
      #pragma unroll
      for (int f = 0; f < F_; ++f) a += zsm[pr][f] * dWih[(size_t)colg*F_ + f];
      b1sm[pr][cc] = a;
    }
    __syncthreads();
  }

  // decoder B fragments (W_eff), K = 1024 (256 VGPR, pinned)
  #pragma unroll
  for (int q = 0; q < 32; ++q) {
    #pragma unroll
    for (int n = 0; n < 2; ++n) {
      int nt = nh*2 + n;
      bw[q][n] = *(const f16x8*)(bpd + ((((size_t)wgN*32 + q)*4 + nt)*64 + l)*8);
      asm volatile("" : "+v"(bw[q][n]));
    }
  }

  // ---------------- decoder: 128 steps ----------------
  for (int t = 1; t <= T_; ++t) {
    const f16* hsrc = ((t - 1) & 1) ? hb1 : hb0;
    f16*       hdst = ((t - 1) & 1) ? hb0 : hb1;
    const f16* hr = hsrc + (size_t)arow*H_ + koff;
    f32x4 acc0 = {0.f,0.f,0.f,0.f}, acc1 = {0.f,0.f,0.f,0.f};
    ISSUE4(0, hr, 0);
    ISSUE4(1, hr, 4);
    ISSUE4(2, hr, 8);
    WAITV(8); MFMA8(0, 0);  ISSUE4(0, hr, 12);
    WAITV(8); MFMA8(1, 4);  ISSUE4(1, hr, 16);
    WAITV(8); MFMA8(2, 8);  ISSUE4(2, hr, 20);
    WAITV(8); MFMA8(0, 12); ISSUE4(0, hr, 24);
    WAITV(8); MFMA8(1, 16); ISSUE4(1, hr, 28);
    WAITV(8); MFMA8(2, 20);
    WAITV(4); MFMA8(0, 24);
    WAITV(0); MFMA8(1, 28);
    EPILOGUE();
    POINTWISE(bslD, (t == 1), true, t);
    if (t < T_) GRIDBAR(255 + t);
  }
}

// =================== final out projection: out = hist @ out_W^T + out_b ===================
__global__ __launch_bounds__(256) void k_out(const char* __restrict__ ws,
                                             const float* __restrict__ ob,
                                             float* __restrict__ out)
{
  const f16* hist = (const f16*)(ws + HIST_OFF);
  const f16* owp  = (const f16*)(ws + OWP_OFF);
  int tid = threadIdx.x; int w = tid >> 6, l = tid & 63;
  int r0 = blockIdx.x*64 + w*16;
  f32x4 acc[4] = {{0.f,0.f,0.f,0.f},{0.f,0.f,0.f,0.f},{0.f,0.f,0.f,0.f},{0.f,0.f,0.f,0.f}};
  for (int q = 0; q < 32; ++q) {
    int row = r0 + (l & 15);
    f16x8 a = *(const f16x8*)(hist + (size_t)row*H_ + q*32 + ((l >> 4) << 3));
    #pragma unroll
    for (int nt = 0; nt < 4; ++nt) {
      f16x8 b = *(const f16x8*)(owp + (((size_t)(q*4 + nt))*64 + l)*8);
      acc[nt] = __builtin_amdgcn_mfma_f32_16x16x32_f16(a, b, acc[nt], 0, 0, 0);
    }
  }
  #pragma unroll
  for (int nt = 0; nt < 4; ++nt) {
    #pragma unroll
    for (int reg = 0; reg < 4; ++reg) {
      int rr = r0 + ((l >> 4) << 2) + reg;
      int bb = rr & 127; int tt = rr >> 7;   // hist row = (t-1)*B + b
      int f = nt*16 + (l & 15);
      out[((size_t)bb*T_ + tt)*F_ + f] = acc[nt][reg] + ob[f];
    }
  }
}

// =================== host launcher ===================
extern "C" void kernel_launch(void* const* d_in, const int* in_sizes, int n_in,
                              void* d_out, int out_size, void* d_ws, size_t ws_size,
                              hipStream_t stream)
{
  const float* x     = (const float*)d_in[0];
  const float* eWih  = (const float*)d_in[1];
  const float* eWhh  = (const float*)d_in[2];
  const float* eb_ih = (const float*)d_in[3];
  const float* eb_hh = (const float*)d_in[4];
  const float* dW    = (const float*)d_in[5];
  const float* dbv   = (const float*)d_in[6];
  const float* dWih  = (const float*)d_in[7];
  const float* dWhh  = (const float*)d_in[8];
  const float* db_ih = (const float*)d_in[9];
  const float* db_hh = (const float*)d_in[10];
  const float* oW    = (const float*)d_in[11];
  const float* ob    = (const float*)d_in[12];
  char* ws = (char*)d_ws;

  hipLaunchKernelGGL(k_prep, dim3(2048), dim3(256), 0, stream,
                     x, eWih, eWhh, eb_ih, eb_hh, dW, dbv, dWih, db_ih, db_hh, oW, ob, ws);
  hipLaunchKernelGGL(k_packdec, dim3(1024), dim3(256), 0, stream, dWih, dWhh, oW, ws);

  const f16* x16p = (const f16*)(ws + X16_OFF);
  const f16* bpep = (const f16*)(ws + BPE_OFF);
  const f16* bpdp = (const f16*)(ws + BPD_OFF);
  const float* dwtp = (const float*)(ws + DWT_OFF);
  const float* benp = (const float*)(ws + BEN_OFF);
  const float* bdep = (const float*)(ws + BDE_OFF);
  const float* bbap = (const float*)(ws + BBA_OFF);
  f16* hb0p = (f16*)(ws + HB0_OFF);
  f16* hb1p = (f16*)(ws + HB1_OFF);
  f16* histp = (f16*)(ws + HIST_OFF);
  u32* barp = (u32*)(ws + BAR_OFF);

  hipLaunchKernelGGL(k_lstm, dim3(256), dim3(256), 0, stream,
                     x16p, bpep, bpdp, dwtp, benp, bdep, bbap, dbv, dWih,
                     hb0p, hb1p, histp, barp);

  hipLaunchKernelGGL(k_out, dim3(256), dim3(256), 0, stream,
                     (const char*)ws, ob, (float*)d_out);
}

// Round 8
// 1579.290 us; speedup vs baseline: 1.9108x; 1.9108x over previous
//
#include <hip/hip_runtime.h>
#include <hip/hip_fp16.h>
#include <math.h>

typedef _Float16 f16;
typedef __attribute__((ext_vector_type(8))) _Float16 f16x8;
typedef __attribute__((ext_vector_type(4))) float f32x4;
typedef unsigned int u32;

#define B_ 128
#define S_ 256
#define I_ 128
#define H_ 1024
#define G_ 4096
#define T_ 128
#define F_ 64

// ---------------- workspace layout (bytes) ----------------
#define BAR_OFF   0ull
#define HB0_OFF   4096ull
#define HB1_OFF   (HB0_OFF + 262144ull)
#define X16_OFF   (HB1_OFF + 262144ull)          // [S][B][I] f16
#define BPE_OFF   (X16_OFF + 8388608ull)         // enc pack: [32 wgN][4 w][9 q][8 ct][64][8] f16
#define BPD_OFF   (BPE_OFF + 9437184ull)         // dec pack: [32 wgN][4 w][8 q][8 ct][64][8] f16
#define DWT_OFF   (BPD_OFF + 8388608ull)         // (dense_W - out_W)^T : [1024][64] f32
#define BEN_OFF   (DWT_OFF + 262144ull)          // enc bias [4096] f32
#define BDE_OFF   (BEN_OFF + 16384ull)           // dec bias (t>=2) [4096] f32
#define BBA_OFF   (BDE_OFF + 16384ull)           // dec base bias (b_ih+b_hh) [4096] f32
#define OWP_OFF   (BBA_OFF + 16384ull)           // out_W pack [32][4][64][8] f16
#define HIST_OFF  (OWP_OFF + 131072ull)          // dec h history [128][128][1024] f16
// total ~60.7 MB

// =================== prep kernel 1 ===================
__global__ void k_prep(const float* __restrict__ x,
                       const float* __restrict__ eWih, const float* __restrict__ eWhh,
                       const float* __restrict__ eb_ih, const float* __restrict__ eb_hh,
                       const float* __restrict__ dW,   const float* __restrict__ db,
                       const float* __restrict__ dWih, const float* __restrict__ db_ih,
                       const float* __restrict__ db_hh,
                       const float* __restrict__ oW,   const float* __restrict__ ob,
                       char* ws)
{
  u32*  bar = (u32*)(ws + BAR_OFF);
  f16*  h0  = (f16*)(ws + HB0_OFF);
  f16*  x16 = (f16*)(ws + X16_OFF);
  f16*  bpe = (f16*)(ws + BPE_OFF);
  float* dwt = (float*)(ws + DWT_OFF);
  float* ben = (float*)(ws + BEN_OFF);
  float* bde = (float*)(ws + BDE_OFF);
  float* bba = (float*)(ws + BBA_OFF);
  f16*  owp = (f16*)(ws + OWP_OFF);

  int tid = blockIdx.x*blockDim.x + threadIdx.x;
  int np  = gridDim.x*blockDim.x;

  // re-zero barrier + ticket state every call (graph replay determinism)
  for (int i = tid; i < 1024; i += np) bar[i] = 0u;
  for (int i = tid; i < B_*H_; i += np) h0[i] = (f16)0.f;

  for (int i = tid; i < S_*B_*I_; i += np) {
    int ii = i & 127; int b = (i >> 7) & 127; int s = i >> 14;
    x16[i] = (f16)x[((size_t)b*S_ + s)*I_ + ii];
  }

  for (int g = tid; g < G_; g += np) {
    ben[g] = eb_ih[g] + eb_hh[g];
    float base = db_ih[g] + db_hh[g];
    bba[g] = base;
    float acc = base;
    for (int f = 0; f < F_; ++f) acc += ob[f] * dWih[(size_t)g*F_ + f];
    bde[g] = acc;
  }

  for (int i = tid; i < H_*F_; i += np) {
    int f = i & 63; int k = i >> 6;
    dwt[i] = dW[(size_t)f*H_ + k] - oW[(size_t)f*H_ + k];
  }

  // encoder pack: [wgN 0..31][w 0..3][q 0..8][ct 0..7][lane][8]
  // k = w*288 + q*32 + (lane>>4)*8 + j ; colg = (ct>>1)*1024 + wgN*32 + (ct&1)*16 + (lane&15)
  for (int i = tid; i < 32*4*9*8*64*8; i += np) {
    int j = i & 7; int lane = (i >> 3) & 63; int ct = (i >> 9) & 7;
    int rest = i >> 12;          // 0..1151
    int q = rest % 9; int rest2 = rest / 9;
    int w = rest2 & 3; int wgN = rest2 >> 2;
    int k = w*288 + q*32 + ((lane >> 4) << 3) + j;
    int colg = (ct >> 1)*1024 + wgN*32 + (ct & 1)*16 + (lane & 15);
    float v = (k < 128) ? eWih[(size_t)colg*I_ + k] : eWhh[(size_t)colg*H_ + (k - 128)];
    bpe[i] = (f16)v;
  }

  // out_W pack for final GEMM (unchanged, r4-validated)
  for (int i = tid; i < 32*4*64*8; i += np) {
    int j = i & 7; int lane = (i >> 3) & 63; int nt = (i >> 9) & 3; int q = i >> 11;
    int f = nt*16 + (lane & 15);
    int k = q*32 + ((lane >> 4) << 3) + j;
    owp[i] = (f16)oW[(size_t)f*H_ + k];
  }
}

// =================== prep kernel 2: W_eff = dec_W_hh + dec_W_ih @ out_W ===================
__global__ void k_packdec(const float* __restrict__ dWih, const float* __restrict__ dWhh,
                          const float* __restrict__ oW, char* ws)
{
  f16* bpd = (f16*)(ws + BPD_OFF);
  __shared__ float sW[4][64];
  int cg0 = blockIdx.x * 4;
  for (int i = threadIdx.x; i < 256; i += 256)
    sW[i >> 6][i & 63] = dWih[(size_t)(cg0 + (i >> 6))*64 + (i & 63)];
  __syncthreads();
  for (int u = 0; u < 4; ++u) {
    int colg = cg0 + u;
    for (int k = threadIdx.x; k < 1024; k += 256) {
      float acc = dWhh[(size_t)colg*1024 + k];
      #pragma unroll
      for (int f = 0; f < 64; ++f) acc += sW[u][f] * oW[(size_t)f*1024 + k];
      // dec pack: [wgN][w][q 0..7][ct][lane][8], k = w*256 + q*32 + hi*8 + j
      int g = colg >> 10; int c10 = colg & 1023;
      int wgN = c10 >> 5, uhalf = (c10 >> 4) & 1, cl = c10 & 15;
      int ct = g*2 + uhalf;
      int w = k >> 8, q = (k >> 5) & 7, hi = (k >> 3) & 3, j = k & 7;
      int lane = hi*16 + cl;
      bpd[(((((size_t)wgN*4 + w)*8 + q)*8 + ct)*64 + lane)*8 + j] = (f16)acc;
    }
  }
}

// =================== persistent LSTM kernel (XCD-local groups) ===================
// grid 256 = 1 WG/CU (register pressure forces 1 block/CU => exactly 32 WGs/XCD).
// Group = XCD (via HW_REG_XCC_ID); slot 0..31 via per-XCD atomic ticket.
// WG: 16 batch rows (grp*16..+16) x 32 hidden units (wgN*32..+32) = 128 gate cols.
// Wave w owns K-chunk w (288 enc / 256 dec): 9 (8) A-loads + 72 (64) MFMA per step,
// partial sums combined through LDS. h-exchange is XCD-local: sc0 (L1-bypass, L2-served).

#define LDg(DST, PTR) \
  asm volatile("global_load_dwordx4 %0, %1, off sc0" : "=v"(DST) : "v"(PTR))

#define WAITV(N) do { \
    asm volatile("s_waitcnt vmcnt(" #N ")" ::: "memory"); \
    __builtin_amdgcn_sched_barrier(0); \
  } while (0)

#define MFMA_Q(Q) do { \
    _Pragma("unroll") \
    for (int ct_ = 0; ct_ < 8; ++ct_) \
      acc[ct_] = __builtin_amdgcn_mfma_f32_16x16x32_f16(af[Q], bw[Q][ct_], acc[ct_], 0,0,0); \
  } while (0)

#define EPILOGUE() do { \
    _Pragma("unroll") \
    for (int ct_ = 0; ct_ < 8; ++ct_) { \
      _Pragma("unroll") \
      for (int reg_ = 0; reg_ < 4; ++reg_) \
        gsm4[w][((l >> 4) << 2) + reg_][ct_*16 + (l & 15)] = acc[ct_][reg_]; \
    } \
    __syncthreads(); \
  } while (0)

#define SIGF(X) (1.f/(1.f + __expf(-(X))))
#define TANHF(X) ({ float e2_ = __expf(2.f*(X)); 1.f - 2.f/(e2_ + 1.f); })

// pointwise: thread -> row r=tid>>4 (0..15), units u2,(u2+1), u2=(tid&15)*2.
#define POINTWISE(BSL, USEB1, DOHIST, TT) do { \
    float hn2_[2]; \
    _Pragma("unroll") \
    for (int uu_ = 0; uu_ < 2; ++uu_) { \
      int u_ = pu2 + uu_; \
      int ci_ = ((u_ >> 4) << 4) + (u_ & 15); \
      float gv_[4]; \
      _Pragma("unroll") \
      for (int g_ = 0; g_ < 4; ++g_) { \
        int ix_ = g_*32 + ci_; \
        float s_ = (gsm4[0][pr][ix_] + gsm4[1][pr][ix_]) \
                 + (gsm4[2][pr][ix_] + gsm4[3][pr][ix_]); \
        gv_[g_] = s_ + ((USEB1) ? b1sm[pr][ix_] : (BSL)[ix_]); \
      } \
      float si_ = SIGF(gv_[0]); \
      float sf_ = SIGF(gv_[1]); \
      float sg_ = TANHF(gv_[2]); \
      float so_ = SIGF(gv_[3]); \
      float cn_ = sf_*(uu_ ? creg1 : creg0) + si_*sg_; \
      if (uu_) creg1 = cn_; else creg0 = cn_; \
      hn2_[uu_] = so_ * TANHF(cn_); \
    } \
    u32 hv_ = ((u32)__builtin_bit_cast(unsigned short, (f16)hn2_[0])) \
            | (((u32)__builtin_bit_cast(unsigned short, (f16)hn2_[1])) << 16); \
    f16* hp_ = hdst + (size_t)(grow0 + pr)*H_ + wgN*32 + pu2; \
    asm volatile("global_store_dword %0, %1, off sc0" :: "v"(hp_), "v"(hv_) : "memory"); \
    if (DOHIST) *(u32*)(hist + ((size_t)((TT) - 1)*B_ + grow0 + pr)*H_ + wgN*32 + pu2) = hv_; \
  } while (0)

// group barrier: 32 WGs of this XCD. counter+flag relaxed agent atomics.
#define GRIDBAR(ID) do { \
    asm volatile("s_waitcnt vmcnt(0)" ::: "memory"); \
    __syncthreads(); \
    if (tid == 0) { \
      u32 a = __hip_atomic_fetch_add(cnt, 1u, __ATOMIC_RELAXED, __HIP_MEMORY_SCOPE_AGENT); \
      if (a == (u32)((ID)*32 + 31)) { \
        __hip_atomic_store(flg, (u32)((ID) + 1), __ATOMIC_RELAXED, __HIP_MEMORY_SCOPE_AGENT); \
      } \
      while (__hip_atomic_load(flg, __ATOMIC_RELAXED, __HIP_MEMORY_SCOPE_AGENT) < (u32)((ID) + 1)) { \
        __builtin_amdgcn_s_sleep(1); \
      } \
    } \
    __syncthreads(); \
  } while (0)

__global__ __launch_bounds__(256, 1) void k_lstm(
    const f16* __restrict__ x16, const f16* __restrict__ bpe, const f16* __restrict__ bpd,
    const float* __restrict__ dwt, const float* __restrict__ ben, const float* __restrict__ bde,
    const float* __restrict__ bba, const float* __restrict__ db,  const float* __restrict__ dWih,
    f16* hb0, f16* hb1, f16* hist, u32* bar)
{
  __shared__ float gsm4[4][16][132];   // per-wave partial gates (stride 132: rows 4 apart -> +16 banks)
  __shared__ f16   hstage[16][1024];   // phase-Y h_n staging
  __shared__ float b1sm[16][132];
  __shared__ float zsm[16][64];
  __shared__ float bslE[128], bslD[128];
  __shared__ u32 s_grpslot;

  const int tid = threadIdx.x;
  const int w = tid >> 6, l = tid & 63;

  // ---- XCD discovery + ticket ----
  if (tid == 0) {
    u32 xcc;
    asm volatile("s_getreg_b32 %0, hwreg(HW_REG_XCC_ID)" : "=s"(xcc));
    xcc &= 7u;
    u32 slot = __hip_atomic_fetch_add(bar + 512 + xcc*32, 1u,
                                      __ATOMIC_RELAXED, __HIP_MEMORY_SCOPE_AGENT);
    s_grpslot = (xcc << 8) | (slot & 31u);
  }
  __syncthreads();
  const int grp = s_grpslot >> 8;      // 0..7  = XCD = batch tile
  const int wgN = s_grpslot & 255;     // 0..31 = hidden-unit tile
  const int grow0 = grp * 16;
  const int arow  = grow0 + (l & 15);
  const int koff  = (l >> 4) << 3;
  const int pr  = tid >> 4;            // pointwise row
  const int pu2 = (tid & 15) * 2;      // pointwise unit pair
  u32* flg = bar + grp*32;
  u32* cnt = bar + 256 + grp*32;

  for (int cc = tid; cc < 128; cc += 256) {
    int colg = (cc >> 5)*1024 + wgN*32 + ((cc >> 4) & 1)*16 + (cc & 15);
    bslE[cc] = ben[colg];
    bslD[cc] = bde[colg];
  }

  // encoder B fragments: wave w -> K-chunk w: bw[9][8] (288 VGPR)
  f16x8 bw[9][8];
  #pragma unroll
  for (int q = 0; q < 9; ++q) {
    #pragma unroll
    for (int ct = 0; ct < 8; ++ct) {
      bw[q][ct] = *(const f16x8*)(bpe + (((((size_t)wgN*4 + w)*9 + q)*8 + ct)*64 + l)*8);
      asm volatile("" : "+v"(bw[q][ct]));
    }
  }
  float creg0 = 0.f, creg1 = 0.f;
  f16x8 af[9];
  __syncthreads();

  // ---------------- encoder: 256 steps, K = 128(x) + 1024(h) ----------------
  for (int t = 0; t < S_; ++t) {
    const f16* hsrc = (t & 1) ? hb1 : hb0;
    f16*       hdst = (t & 1) ? hb0 : hb1;
    const f16* hr = hsrc + (size_t)arow*H_ + koff;
    f32x4 acc[8] = {{0,0,0,0},{0,0,0,0},{0,0,0,0},{0,0,0,0},
                    {0,0,0,0},{0,0,0,0},{0,0,0,0},{0,0,0,0}};
    if (w == 0) {
      const f16* xr = x16 + ((size_t)t*B_ + arow)*I_ + koff;
      LDg(af[0], xr);        LDg(af[1], xr + 32);   LDg(af[2], xr + 64);  LDg(af[3], xr + 96);
      LDg(af[4], hr);        LDg(af[5], hr + 32);   LDg(af[6], hr + 64);
      LDg(af[7], hr + 96);   LDg(af[8], hr + 128);
    } else {
      const f16* hw = hr + (w*288 - 128);
      LDg(af[0], hw);        LDg(af[1], hw + 32);   LDg(af[2], hw + 64);  LDg(af[3], hw + 96);
      LDg(af[4], hw + 128);  LDg(af[5], hw + 160);  LDg(af[6], hw + 192);
      LDg(af[7], hw + 224);  LDg(af[8], hw + 256);
    }
    WAITV(8); MFMA_Q(0);
    WAITV(7); MFMA_Q(1);
    WAITV(6); MFMA_Q(2);
    WAITV(5); MFMA_Q(3);
    WAITV(4); MFMA_Q(4);
    WAITV(3); MFMA_Q(5);
    WAITV(2); MFMA_Q(6);
    WAITV(1); MFMA_Q(7);
    WAITV(0); MFMA_Q(8);
    EPILOGUE();
    POINTWISE(bslE, false, false, t);
    GRIDBAR(t);
  }

  // ---------------- phase Y: z = h_n (dense_W - out_W)^T + dense_b ; bias1 ----------------
  {
    // stage h_n (group-local, L2) into LDS
    int sr = tid >> 4, c0 = (tid & 15) * 64;
    const f16* hp = hb0 + (size_t)(grow0 + sr)*H_ + c0;
    f16x8 tmp[8];
    #pragma unroll
    for (int i = 0; i < 8; ++i) LDg(tmp[i], hp + i*8);
    WAITV(0);
    #pragma unroll
    for (int i = 0; i < 8; ++i) *(f16x8*)&hstage[sr][c0 + i*8] = tmp[i];
    __syncthreads();

    int f0 = (tid & 15) * 4;
    f32x4 za = *(const f32x4*)&db[f0];
    for (int kb = 0; kb < 128; ++kb) {
      f16x8 hv = *(const f16x8*)&hstage[pr][kb*8];
      #pragma unroll
      for (int j = 0; j < 8; ++j) {
        float h = (float)hv[j];
        f32x4 dv = *(const f32x4*)&dwt[(kb*8 + j)*F_ + f0];
        za += h * dv;
      }
    }
    *(f32x4*)&zsm[pr][f0] = za;
    __syncthreads();

    int cc0 = (tid & 15) * 8;
    for (int u = 0; u < 8; ++u) {
      int cc = cc0 + u;
      int colg = (cc >> 5)*1024 + wgN*32 + ((cc >> 4) & 1)*16 + (cc & 15);
      float a = bba[colg];
      #pragma unroll
      for (int f = 0; f < F_; ++f) a += zsm[pr][f] * dWih[(size_t)colg*F_ + f];
      b1sm[pr][cc] = a;
    }
    __syncthreads();
  }

  // decoder B fragments (W_eff): bw[8][8] (256 VGPR)
  #pragma unroll
  for (int q = 0; q < 8; ++q) {
    #pragma unroll
    for (int ct = 0; ct < 8; ++ct) {
      bw[q][ct] = *(const f16x8*)(bpd + (((((size_t)wgN*4 + w)*8 + q)*8 + ct)*64 + l)*8);
      asm volatile("" : "+v"(bw[q][ct]));
    }
  }

  // ---------------- decoder: 128 steps, K = 1024 ----------------
  for (int t = 1; t <= T_; ++t) {
    const f16* hsrc = ((t - 1) & 1) ? hb1 : hb0;
    f16*       hdst = ((t - 1) & 1) ? hb0 : hb1;
    const f16* hw = hsrc + (size_t)arow*H_ + koff + w*256;
    f32x4 acc[8] = {{0,0,0,0},{0,0,0,0},{0,0,0,0},{0,0,0,0},
                    {0,0,0,0},{0,0,0,0},{0,0,0,0},{0,0,0,0}};
    LDg(af[0], hw);        LDg(af[1], hw + 32);   LDg(af[2], hw + 64);  LDg(af[3], hw + 96);
    LDg(af[4], hw + 128);  LDg(af[5], hw + 160);  LDg(af[6], hw + 192); LDg(af[7], hw + 224);
    WAITV(7); MFMA_Q(0);
    WAITV(6); MFMA_Q(1);
    WAITV(5); MFMA_Q(2);
    WAITV(4); MFMA_Q(3);
    WAITV(3); MFMA_Q(4);
    WAITV(2); MFMA_Q(5);
    WAITV(1); MFMA_Q(6);
    WAITV(0); MFMA_Q(7);
    EPILOGUE();
    POINTWISE(bslD, (t == 1), true, t);
    if (t < T_) GRIDBAR(255 + t);
  }
}

// =================== final out projection: out = hist @ out_W^T + out_b ===================
__global__ __launch_bounds__(256) void k_out(const char* __restrict__ ws,
                                             const float* __restrict__ ob,
                                             float* __restrict__ out)
{
  const f16* hist = (const f16*)(ws + HIST_OFF);
  const f16* owp  = (const f16*)(ws + OWP_OFF);
  int tid = threadIdx.x; int w = tid >> 6, l = tid & 63;
  int r0 = blockIdx.x*64 + w*16;
  f32x4 acc[4] = {{0.f,0.f,0.f,0.f},{0.f,0.f,0.f,0.f},{0.f,0.f,0.f,0.f},{0.f,0.f,0.f,0.f}};
  for (int q = 0; q < 32; ++q) {
    int row = r0 + (l & 15);
    f16x8 a = *(const f16x8*)(hist + (size_t)row*H_ + q*32 + ((l >> 4) << 3));
    #pragma unroll
    for (int nt = 0; nt < 4; ++nt) {
      f16x8 b = *(const f16x8*)(owp + (((size_t)(q*4 + nt))*64 + l)*8);
      acc[nt] = __builtin_amdgcn_mfma_f32_16x16x32_f16(a, b, acc[nt], 0, 0, 0);
    }
  }
  #pragma unroll
  for (int nt = 0; nt < 4; ++nt) {
    #pragma unroll
    for (int reg = 0; reg < 4; ++reg) {
      int rr = r0 + ((l >> 4) << 2) + reg;
      int bb = rr & 127; int tt = rr >> 7;   // hist row = (t-1)*B + b
      int f = nt*16 + (l & 15);
      out[((size_t)bb*T_ + tt)*F_ + f] = acc[nt][reg] + ob[f];
    }
  }
}

// =================== host launcher ===================
extern "C" void kernel_launch(void* const* d_in, const int* in_sizes, int n_in,
                              void* d_out, int out_size, void* d_ws, size_t ws_size,
                              hipStream_t stream)
{
  const float* x     = (const float*)d_in[0];
  const float* eWih  = (const float*)d_in[1];
  const float* eWhh  = (const float*)d_in[2];
  const float* eb_ih = (const float*)d_in[3];
  const float* eb_hh = (const float*)d_in[4];
  const float* dW    = (const float*)d_in[5];
  const float* dbv   = (const float*)d_in[6];
  const float* dWih  = (const float*)d_in[7];
  const float* dWhh  = (const float*)d_in[8];
  const float* db_ih = (const float*)d_in[9];
  const float* db_hh = (const float*)d_in[10];
  const float* oW    = (const float*)d_in[11];
  const float* ob    = (const float*)d_in[12];
  char* ws = (char*)d_ws;

  hipLaunchKernelGGL(k_prep, dim3(2048), dim3(256), 0, stream,
                     x, eWih, eWhh, eb_ih, eb_hh, dW, dbv, dWih, db_ih, db_hh, oW, ob, ws);
  hipLaunchKernelGGL(k_packdec, dim3(1024), dim3(256), 0, stream, dWih, dWhh, oW, ws);

  const f16* x16p = (const f16*)(ws + X16_OFF);
  const f16* bpep = (const f16*)(ws + BPE_OFF);
  const f16* bpdp = (const f16*)(ws + BPD_OFF);
  const float* dwtp = (const float*)(ws + DWT_OFF);
  const float* benp = (const float*)(ws + BEN_OFF);
  const float* bdep = (const float*)(ws + BDE_OFF);
  const float* bbap = (const float*)(ws + BBA_OFF);
  f16* hb0p = (f16*)(ws + HB0_OFF);
  f16* hb1p = (f16*)(ws + HB1_OFF);
  f16* histp = (f16*)(ws + HIST_OFF);
  u32* barp = (u32*)(ws + BAR_OFF);

  hipLaunchKernelGGL(k_lstm, dim3(256), dim3(256), 0, stream,
                     x16p, bpep, bpdp, dwtp, benp, bdep, bbap, dbv, dWih,
                     hb0p, hb1p, histp, barp);

  hipLaunchKernelGGL(k_out, dim3(256), dim3(256), 0, stream,
                     (const char*)ws, ob, (float*)d_out);
}